// Round 18
// baseline (309.228 us; speedup 1.0000x reference)
//
#include <hip/hip_runtime.h>
#include <hip/hip_bf16.h>

// AlignmentContrastiveLoss on MI355X.
//   K1 normalize_pack: fp32 L2-normalize, drop CLS/special tokens, cast bf16.
//      A DENSE [256][36][1024]; B PADDED [256][32][1024]. 2 rows/wave (R16).
//   K2 gemm_scores (R18): R14's verified core (144x256 tile, 4 waves,
//      batched af[9]+bfr[4] -> unbroken 36-MFMA cluster, zero-conflict
//      swizzle) x the ONE untested schedule cell: stage-early DOUBLE-BUFFER
//      with plain __syncthreads. BK=32, 2 x 25.6 KB buffers (51200 B total =
//      same LDS as R14 -> 2 blocks/CU preserved). Per iter: {stage slice
//      k+1 -> buf^1; compute slice k from buf; __syncthreads()} -- the
//      barrier's implicit vmcnt(0) drains DMAs issued a full compute phase
//      earlier (hidden), vs R14 where the drain directly follows the issue.
//      No inline-asm sync, no fences (R15's loss), no interleaved reads
//      (R9's loss), no 64B-row conflicts (R5's loss).
//      LDS geometry (R15-refchecked, absmax 0): 128-B lines pair rows
//      (2L, 2L+1); phys_slot = logical ^ (line&7); logical = (row&1)*4 +
//      chunk16. Inverse-swizzled per-lane global source; DMA dest linear.
//   K3 loss_fused: 64 blocks, block-partial reduction + one atomicAdd.

typedef __attribute__((ext_vector_type(8))) short bf16x8;
typedef __attribute__((ext_vector_type(4))) float f32x4;

#define NB   256
#define DIM  1024
#define LI   36     // valid image regions (dense pack stride)
#define LIP  36     // A pack stride (dense)
#define LS   30     // valid words per sentence
#define LSP  32     // B pack stride (padded to 2 x 16)
#define ABYTES 9216    // A region bytes per buffer (144 rows x 64 B)
#define BUFB   25600   // buffer bytes: A 9 KB + B 16 KB (256 rows x 64 B)
#define NSLICE 32      // K / BK = 1024 / 32

static __device__ inline ushort f2bf(float x) {
    union { __hip_bfloat16 h; ushort u; } cvt;
    cvt.h = __float2bfloat16(x);
    return cvt.u;
}

static __device__ __forceinline__ void gload_lds16(const void* g, void* l) {
    __builtin_amdgcn_global_load_lds(
        (const __attribute__((address_space(1))) void*)g,
        (__attribute__((address_space(3))) void*)l, 16, 0, 0);
}

// Two rows per wave (independent chains for ILP). Rows 0..9215 -> im'
// (dense); rows 9216..17407 -> s' ([256][32], word slots 30,31 zeroed).
__global__ __launch_bounds__(256) void normalize_pack(
    const float* __restrict__ im, const float* __restrict__ sq,
    short* __restrict__ imp, short* __restrict__ sp)
{
    const int gw   = (blockIdx.x * 256 + threadIdx.x) >> 6;   // wave id
    const int lane = threadIdx.x & 63;
    const int NIM  = NB * LI;   // 9216 dense image rows

    const float* src[2];
    short* dst[2];
    #pragma unroll
    for (int rr = 0; rr < 2; ++rr) {
        const int row = gw * 2 + rr;                 // 0..17407
        if (row < NIM) {
            int b = row / LI, i = row - b * LI;
            dst[rr] = imp + (size_t)row * DIM;
            src[rr] = im + ((size_t)b * 37 + i + 1) * DIM;   // drop CLS
        } else {
            int g2 = row - NIM;
            int b = g2 >> 5, j = g2 & 31;
            dst[rr] = sp + (size_t)g2 * DIM;
            src[rr] = (j < LS) ? (sq + ((size_t)b * 33 + j + 1) * DIM)
                               : nullptr;            // pad word slot
        }
    }

    float4 v[2][4];
    float ss[2] = {0.f, 0.f};
    #pragma unroll
    for (int rr = 0; rr < 2; ++rr) {
        if (src[rr]) {
            const float4* s4 = (const float4*)src[rr];
            #pragma unroll
            for (int t = 0; t < 4; ++t) {
                float4 x = s4[lane + 64 * t];
                v[rr][t] = x;
                ss[rr] += x.x * x.x + x.y * x.y + x.z * x.z + x.w * x.w;
            }
        }
    }
    // two interleaved (independent) shuffle-reduce chains
    #pragma unroll
    for (int o = 32; o >= 1; o >>= 1) {
        ss[0] += __shfl_xor(ss[0], o, 64);
        ss[1] += __shfl_xor(ss[1], o, 64);
    }
    #pragma unroll
    for (int rr = 0; rr < 2; ++rr) {
        if (src[rr]) {
            const float scale = 1.0f / fmaxf(sqrtf(ss[rr]), 1e-12f);
            ushort4* d4 = (ushort4*)dst[rr];
            #pragma unroll
            for (int t = 0; t < 4; ++t) {
                float4 x = v[rr][t];
                ushort4 o;
                o.x = f2bf(x.x * scale);
                o.y = f2bf(x.y * scale);
                o.z = f2bf(x.z * scale);
                o.w = f2bf(x.w * scale);
                d4[lane + 64 * t] = o;
            }
        } else {
            uint4 z = {0u, 0u, 0u, 0u};
            uint4* d4 = (uint4*)dst[rr];
            d4[lane] = z;
            d4[lane + 64] = z;
        }
    }
}

// Block: 256 threads = 4 waves. blockIdx.x -> 4 images (144 dense rows),
// blockIdx.y -> 8 sentences (256 padded rows). Wave w owns N-tiles 4w..4w+3,
// all 9 M-tiles.
//
// Per 25.6 KB buffer (BK=32): A rows 0..143 as lines 0..71 (line L = rows
// 2L,2L+1), B rows 0..255 as lines 0..127 at byte ABYTES. Line = 128 B = 8
// slots of 16 B; phys_slot = logical ^ (line&7); logical = (row&1)*4 + ch,
// ch = 16-B quarter of the row's 64-B k-slice.
// Staging chunk = 1 KB = 8 lines = 16 rows; lane i -> (line i>>3, phys i&7)
// linear; logical s_i = (i&7)^(i>>3); global row = r0 + 2*(i>>3) + (s_i>>2),
// byte (s_i&3)*16 within the k-slice. 25 chunks/slice (A 0..8, B 9..24),
// wave w takes chunks {w + 4j} (wave 0: 7, waves 1-3: 6).
// Read: row R = 16*tile + l15, fragment chunk q -> line 8*tile + (l15>>1),
// phys = ((l15&1)*4 + q) ^ ((l15>>1)&7) -- per-lane constant.
__global__ __launch_bounds__(256, 2) void gemm_scores(
    const short* __restrict__ imp, const short* __restrict__ sp,
    const int* __restrict__ im_len, const int* __restrict__ s_len,
    float* __restrict__ scores)
{
    __shared__ __align__(1024) char lds[2 * BUFB];   // 51200 B double buffer

    const int tid  = threadIdx.x;
    const int wave = tid >> 6;
    const int lane = tid & 63;
    const int q    = lane >> 4;
    const int l15  = lane & 15;
    const int b0   = blockIdx.x * 4;
    const int c0   = blockIdx.y * 8;

    f32x4 acc[9][4];
    #pragma unroll
    for (int mt = 0; mt < 9; ++mt)
        #pragma unroll
        for (int t = 0; t < 4; ++t)
            acc[mt][t] = (f32x4){0.f, 0.f, 0.f, 0.f};

    // ---- staging constants (R15-refchecked geometry) ----
    const int i8 = lane >> 3;          // line within the 8-line chunk
    const int ph = lane & 7;           // phys slot (linear LDS dest)
    const int sl = ph ^ i8;            // logical slot
    const int off_lane = (2 * i8 + (sl >> 2)) * 2048 + (sl & 3) * 16;

    const char* baseA = (const char*)imp + (size_t)(b0 * LIP) * 2048;
    const char* baseB = (const char*)sp  + (size_t)(c0 * LSP) * 2048;

    // wave w handles chunks {w + 4j}; j=6 exists only for wave 0 (chunk 24).
    const char* g7[7];
    int l7[7];
    #pragma unroll
    for (int j = 0; j < 7; ++j) {
        const int cid = wave + 4 * j;            // 0..27 (valid < 25)
        if (cid < 9) {
            g7[j] = baseA + cid * (16 * 2048) + off_lane;
            l7[j] = cid * 1024;
        } else {
            const int bc = (cid < 25 ? cid : 9) - 9;   // clamp junk (unused)
            g7[j] = baseB + bc * (16 * 2048) + off_lane;
            l7[j] = ABYTES + bc * 1024;
        }
    }
    const int nst = (wave == 0) ? 7 : 6;   // DMA per wave per slice

    // Read-side swizzled slot byte offset (per-lane constant).
    const int cs2 = (((l15 & 1) * 4 + q) ^ ((l15 >> 1) & 7)) * 16;
    const int lhalf = l15 >> 1;

    auto compute = [&](const char* buf) {
        bf16x8 af[9], bfr[4];
        #pragma unroll
        for (int mt = 0; mt < 9; ++mt)
            af[mt] = *(const bf16x8*)(buf + (8 * mt + lhalf) * 128 + cs2);
        #pragma unroll
        for (int t = 0; t < 4; ++t)
            bfr[t] = *(const bf16x8*)(buf + ABYTES + (8 * (wave * 4 + t) + lhalf) * 128 + cs2);
        #pragma unroll
        for (int mt = 0; mt < 9; ++mt)
            #pragma unroll
            for (int t = 0; t < 4; ++t)
                acc[mt][t] = __builtin_amdgcn_mfma_f32_16x16x32_bf16(
                    af[mt], bfr[t], acc[mt][t], 0, 0, 0);
    };

    // ---- prologue: stage slice 0 into buf0, drain ----
    for (int j = 0; j < nst; ++j) gload_lds16(g7[j], lds + l7[j]);
    __syncthreads();

    // ---- main loop: per iter {stage k+1 -> buf^1; compute k; barrier} ----
    // The barrier's implicit vmcnt(0) drains the stage issued BEFORE this
    // iter's compute -> drain latency hidden under 36 MFMA + 13 ds_reads.
    int cur = 0;
    #pragma unroll 1
    for (int kk = 0; kk < NSLICE; ++kk) {
        if (kk < NSLICE - 1) {
            const int nb = cur ^ 1;
            for (int j = 0; j < nst; ++j)
                gload_lds16(g7[j] + (kk + 1) * 64, lds + nb * BUFB + l7[j]);
        }
        compute(lds + cur * BUFB);
        __syncthreads();
        cur ^= 1;
    }

    // ---- Fused epilogue (R14/R16-verified, absmax 0) ----
    // C/D layout: lane holds col = l15, row = q*4 + r.
    // Packed A row g = mt*16 + q*4 + r; image = (4*mt+q)/9, region = g-36*image.
    // B col: tile-aligned -- sentence = c0 + (nt>>1), word jj = (nt&1)*16+l15.
    int il[4];
    #pragma unroll
    for (int bb = 0; bb < 4; ++bb) il[bb] = im_len[b0 + bb] - 1;   // in [9, 36]

    float sc[4][2] = {{0.f,0.f},{0.f,0.f},{0.f,0.f},{0.f,0.f}};
    #pragma unroll
    for (int t = 0; t < 4; ++t) {
        const int nt = wave * 4 + t;
        const int c  = c0 + (nt >> 1);
        const int sl2 = s_len[c] - 3;                // valid words, in [5, 30]
        const int jj = (nt & 1) * 16 + l15;          // word index within sentence
        const bool jv = (jj < sl2);

        float m[4] = {-3.4e38f, -3.4e38f, -3.4e38f, -3.4e38f};
        #pragma unroll
        for (int mt = 0; mt < 9; ++mt) {
            const int im_lo = (4 * mt) / 9;          // compile-time
            const int im_hi = (4 * mt + 3) / 9;      // compile-time
            const int thr   = 9 * im_hi - 4 * mt;    // q >= thr -> im_hi
            #pragma unroll
            for (int r = 0; r < 4; ++r) {
                const float v = acc[mt][t][r];
                const int base = mt * 16 + q * 4 + r;
                if (im_lo == im_hi) {
                    const int i = base - 36 * im_lo;
                    if (i < il[im_lo]) m[im_lo] = fmaxf(m[im_lo], v);
                } else {
                    const bool hi = (q >= thr);
                    if (!hi) {
                        const int i = base - 36 * im_lo;
                        if (i < il[im_lo]) m[im_lo] = fmaxf(m[im_lo], v);
                    } else {
                        const int i = base - 36 * im_hi;
                        if (i < il[im_hi]) m[im_hi] = fmaxf(m[im_hi], v);
                    }
                }
            }
        }
        #pragma unroll
        for (int bb = 0; bb < 4; ++bb) {
            float mm = m[bb];
            // combine the 4 row-quads -> full max over image bb's regions
            mm = fmaxf(mm, __shfl_xor(mm, 16, 64));
            mm = fmaxf(mm, __shfl_xor(mm, 32, 64));
            // masked (zeroed) entries participate in the max only when il < 36
            if (il[bb] < LI) mm = fmaxf(mm, 0.f);
            float v = (q == 0 && jv) ? mm : 0.f;     // count each column once
            #pragma unroll
            for (int off = 32; off >= 1; off >>= 1) v += __shfl_xor(v, off, 64);
            sc[bb][t >> 1] += v;
        }
    }
    if (lane == 0) {
        #pragma unroll
        for (int bb = 0; bb < 4; ++bb)
            #pragma unroll
            for (int h = 0; h < 2; ++h)
                scores[(b0 + bb) * NB + c0 + wave * 2 + h] = sc[bb][h];
    }
}

// Fused contrastive loss: 64 blocks x 4 waves; wave handles row/col t of the
// score matrix; block-level sum -> one atomicAdd into out[0].
__global__ __launch_bounds__(256) void loss_fused(
    const float* __restrict__ sc, float* __restrict__ out)
{
    const int wave = threadIdx.x >> 6, lane = threadIdx.x & 63;
    const int t = blockIdx.x * 4 + wave;
    const float dt = sc[t * (NB + 1)];
    float rowmax = 0.f, colmax = 0.f;
    #pragma unroll
    for (int p = 0; p < 4; ++p) {
        const int k = lane + 64 * p;
        const float r = sc[t * NB + k];
        const float c = sc[k * NB + t];
        if (k != t) {
            rowmax = fmaxf(rowmax, 0.2f + r - dt);
            colmax = fmaxf(colmax, 0.2f + c - dt);
        }
    }
    #pragma unroll
    for (int o = 32; o >= 1; o >>= 1) {
        rowmax = fmaxf(rowmax, __shfl_xor(rowmax, o, 64));
        colmax = fmaxf(colmax, __shfl_xor(colmax, o, 64));
    }
    __shared__ float red[4];
    if (lane == 0) red[wave] = fmaxf(rowmax, 0.f) + fmaxf(colmax, 0.f);
    __syncthreads();
    if (threadIdx.x == 0)
        atomicAdd(out, red[0] + red[1] + red[2] + red[3]);
}

extern "C" void kernel_launch(void* const* d_in, const int* in_sizes, int n_in,
                              void* d_out, int out_size, void* d_ws, size_t ws_size,
                              hipStream_t stream) {
    const float* im_set = (const float*)d_in[0];
    const float* s_seq  = (const float*)d_in[1];
    const int*   im_len = (const int*)d_in[2];
    const int*   s_len  = (const int*)d_in[3];
    float* out = (float*)d_out;

    char* ws = (char*)d_ws;
    const size_t imp_bytes = (size_t)NB * LIP * DIM * 2;   // 18.9 MB (dense)
    const size_t sp_bytes  = (size_t)NB * LSP * DIM * 2;   // 16.8 MB (padded)
    short* imp    = (short*)ws;
    short* sp     = (short*)(ws + imp_bytes);
    float* scores = (float*)(ws + imp_bytes + sp_bytes);   // 256 KB

    // 17408 rows, two per wave -> 8704 waves -> 2176 blocks
    normalize_pack<<<2176, 256, 0, stream>>>(im_set, s_seq, imp, sp);

    dim3 grid(NB / 4, NB / 8);
    gemm_scores<<<grid, 256, 0, stream>>>(imp, sp, im_len, s_len, scores);

    loss_fused<<<64, 256, 0, stream>>>(scores, out);
}

// Round 19
// 237.897 us; speedup vs baseline: 1.2998x; 1.2998x over previous
//
#include <hip/hip_runtime.h>
#include <hip/hip_bf16.h>

// AlignmentContrastiveLoss on MI355X — session-final configuration (R16).
//   K1 normalize_pack: fp32 L2-normalize, drop CLS/special tokens, cast bf16.
//      A DENSE [256][36][1024]; B PADDED [256][32][1024]. 2 rows/wave (ILP).
//   K2 gemm_scores (verified best: ~150 us, 1030 TF eff, MfmaUtil 46%,
//      zero bank conflicts, no spill): M=144 (4 images x 36 dense),
//      N=256 (8 sentences x 32 padded), K=1024, BK=64, 4 waves, 2-barrier
//      single-buffer schedule, af[9]+bfr[4] batched ds_reads then an
//      unbroken 36-MFMA register cluster. LDS: 128-B row-lines, XOR chunk
//      swizzle phys = logical ^ (row&7), inverse-swizzled global_load_lds
//      source + swizzled ds_read (both-sides rule).
//      Complete rejected-variant ledger (all measured, this session):
//        - counted-vmcnt triple-buffer: 255 us (R8), 233 us batched (R15)
//        - stage-early double-buffer BK=32, plain syncthreads: 230 us (R18)
//        - 288x256 8-wave tile: 174 us (R17; single barrier domain loses
//          cross-block phase decorrelation)
//        - dense-B N=240: 181-229 us (R9/R10)
//        - B direct global->VGPR: 186 us (R13; reg-staging tax)
//        - XCD-chunk swizzle: FETCH x3 on this L3-fit problem (R12)
//        - interleaved per-mt af reads: 26% MfmaUtil vs 46% batched (R9)
//        - 8-wave occupancy split: A-read duplication, 167 us (R3)
//      Causal summary: at 8 waves/CU the two resident blocks' barrier
//      phases decorrelate and already overlap stage/drain with compute
//      (m114 mechanism); every explicit pipeline halves compute-per-barrier
//      (BK=32) and loses more than it hides.
//   K3 loss_fused: 64 blocks, block-partial reduction + one atomicAdd
//      (harness memsets out before the verified launch; fp32 ordering noise
//      ~1e-5 << threshold).

typedef __attribute__((ext_vector_type(8))) short bf16x8;
typedef __attribute__((ext_vector_type(4))) float f32x4;

#define NB   256
#define DIM  1024
#define LI   36     // valid image regions (dense pack stride)
#define LIP  36     // A pack stride (dense)
#define LS   30     // valid words per sentence
#define LSP  32     // B pack stride (padded to 2 x 16)

static __device__ inline ushort f2bf(float x) {
    union { __hip_bfloat16 h; ushort u; } cvt;
    cvt.h = __float2bfloat16(x);
    return cvt.u;
}

static __device__ __forceinline__ void gload_lds16(const void* g, void* l) {
    __builtin_amdgcn_global_load_lds(
        (const __attribute__((address_space(1))) void*)g,
        (__attribute__((address_space(3))) void*)l, 16, 0, 0);
}

// Two rows per wave (independent chains for ILP). Rows 0..9215 -> im'
// (dense); rows 9216..17407 -> s' ([256][32], word slots 30,31 zeroed).
__global__ __launch_bounds__(256) void normalize_pack(
    const float* __restrict__ im, const float* __restrict__ sq,
    short* __restrict__ imp, short* __restrict__ sp)
{
    const int gw   = (blockIdx.x * 256 + threadIdx.x) >> 6;   // wave id
    const int lane = threadIdx.x & 63;
    const int NIM  = NB * LI;   // 9216 dense image rows

    const float* src[2];
    short* dst[2];
    #pragma unroll
    for (int rr = 0; rr < 2; ++rr) {
        const int row = gw * 2 + rr;                 // 0..17407
        if (row < NIM) {
            int b = row / LI, i = row - b * LI;
            dst[rr] = imp + (size_t)row * DIM;
            src[rr] = im + ((size_t)b * 37 + i + 1) * DIM;   // drop CLS
        } else {
            int g2 = row - NIM;
            int b = g2 >> 5, j = g2 & 31;
            dst[rr] = sp + (size_t)g2 * DIM;
            src[rr] = (j < LS) ? (sq + ((size_t)b * 33 + j + 1) * DIM)
                               : nullptr;            // pad word slot
        }
    }

    float4 v[2][4];
    float ss[2] = {0.f, 0.f};
    #pragma unroll
    for (int rr = 0; rr < 2; ++rr) {
        if (src[rr]) {
            const float4* s4 = (const float4*)src[rr];
            #pragma unroll
            for (int t = 0; t < 4; ++t) {
                float4 x = s4[lane + 64 * t];
                v[rr][t] = x;
                ss[rr] += x.x * x.x + x.y * x.y + x.z * x.z + x.w * x.w;
            }
        }
    }
    // two interleaved (independent) shuffle-reduce chains
    #pragma unroll
    for (int o = 32; o >= 1; o >>= 1) {
        ss[0] += __shfl_xor(ss[0], o, 64);
        ss[1] += __shfl_xor(ss[1], o, 64);
    }
    #pragma unroll
    for (int rr = 0; rr < 2; ++rr) {
        if (src[rr]) {
            const float scale = 1.0f / fmaxf(sqrtf(ss[rr]), 1e-12f);
            ushort4* d4 = (ushort4*)dst[rr];
            #pragma unroll
            for (int t = 0; t < 4; ++t) {
                float4 x = v[rr][t];
                ushort4 o;
                o.x = f2bf(x.x * scale);
                o.y = f2bf(x.y * scale);
                o.z = f2bf(x.z * scale);
                o.w = f2bf(x.w * scale);
                d4[lane + 64 * t] = o;
            }
        } else {
            uint4 z = {0u, 0u, 0u, 0u};
            uint4* d4 = (uint4*)dst[rr];
            d4[lane] = z;
            d4[lane + 64] = z;
        }
    }
}

// Block: 256 threads = 4 waves. blockIdx.x -> 4 images (144 dense rows),
// blockIdx.y -> 8 sentences (256 padded rows). Wave w owns N-tiles 4w..4w+3
// (= sentences c0+2w, c0+2w+1), all 9 M-tiles -> score cells wave-private.
//
// LDS: As[144][64], Bs[256][64] bf16; a row's BK=64 k-slice = one 128-B line
// = 8 chunks of 16 B. Swizzle: phys_chunk = logical_chunk ^ (row & 7).
// Staging: one DMA instr = 1 KB = 8 rows; lane i -> row r0+(i>>3), phys
// chunk i&7; global source logical chunk (i&7)^(i>>3) [r0 % 8 == 0].
// Reads: tile row bases are multiples of 16 -> row&7 = l15&7 -> phys chunk
// = (g*4+q) ^ (l15&7), per-lane constant. 8-consecutive-lane b128 groups
// cover all 32 banks exactly once (reads and linear DMA writes) -> measured
// zero conflicts.
__global__ __launch_bounds__(256, 2) void gemm_scores(
    const short* __restrict__ imp, const short* __restrict__ sp,
    const int* __restrict__ im_len, const int* __restrict__ s_len,
    float* __restrict__ scores)
{
    __shared__ short As[144 * 64];   // 18 KB
    __shared__ short Bs[256 * 64];   // 32 KB

    const int tid  = threadIdx.x;
    const int wave = tid >> 6;
    const int lane = tid & 63;
    const int q    = lane >> 4;
    const int l15  = lane & 15;
    const int b0   = blockIdx.x * 4;
    const int c0   = blockIdx.y * 8;

    f32x4 acc[9][4];
    #pragma unroll
    for (int mt = 0; mt < 9; ++mt)
        #pragma unroll
        for (int t = 0; t < 4; ++t)
            acc[mt][t] = (f32x4){0.f, 0.f, 0.f, 0.f};

    // Per-lane staging source constants.
    const int srow   = lane >> 3;             // row within the 8-row chunk
    const int schunk = (lane & 7) ^ srow;     // inverse-swizzled 16B chunk
    const char* gA = (const char*)imp + (size_t)(b0 * LIP) * 2048
                     + srow * 2048 + schunk * 16;
    const char* gB = (const char*)sp + (size_t)(c0 * LSP) * 2048
                     + srow * 2048 + schunk * 16;

    // Read-side swizzled chunk byte offsets (per-lane constants).
    const int cs0 = ((q)     ^ (l15 & 7)) * 16;   // g = 0
    const int cs1 = ((4 + q) ^ (l15 & 7)) * 16;   // g = 1

    const int wa4 = wave * 4;   // A row-blocks: 18 total, 4/wave + 2 extra
    const int wb8 = wave * 8;   // B row-blocks: 32 total, 8/wave

    for (int k0 = 0; k0 < DIM; k0 += 64) {
        const int kb = k0 * 2;   // byte offset of this K-slice within a row
        // stage A: 144 rows x 128 B = 18 DMA instrs
        #pragma unroll
        for (int it = 0; it < 4; ++it) {
            const int rb = wa4 + it;
            gload_lds16(gA + rb * (8 * 2048) + kb, (char*)As + rb * 1024);
        }
        if (wave < 2) {
            const int rb = 16 + wave;
            gload_lds16(gA + rb * (8 * 2048) + kb, (char*)As + rb * 1024);
        }
        // stage B: 256 rows x 128 B = 32 DMA instrs, 8/wave
        #pragma unroll
        for (int it = 0; it < 8; ++it) {
            const int rb = wb8 + it;
            gload_lds16(gB + rb * (8 * 2048) + kb, (char*)Bs + rb * 1024);
        }
        __syncthreads();   // compiler emits vmcnt(0) drain for the DMA
        #pragma unroll
        for (int g = 0; g < 2; ++g) {
            const int cs = g ? cs1 : cs0;
            bf16x8 af[9], bfr[4];
            #pragma unroll
            for (int mt = 0; mt < 9; ++mt)
                af[mt] = *(const bf16x8*)((const char*)As + (mt * 16 + l15) * 128 + cs);
            #pragma unroll
            for (int t = 0; t < 4; ++t)
                bfr[t] = *(const bf16x8*)((const char*)Bs + ((wave * 4 + t) * 16 + l15) * 128 + cs);
            #pragma unroll
            for (int mt = 0; mt < 9; ++mt)
                #pragma unroll
                for (int t = 0; t < 4; ++t)
                    acc[mt][t] = __builtin_amdgcn_mfma_f32_16x16x32_bf16(
                        af[mt], bfr[t], acc[mt][t], 0, 0, 0);
        }
        __syncthreads();
    }

    // ---- Fused epilogue (verified, absmax 0) ----
    // C/D layout: lane holds col = l15, row = q*4 + r.
    // Packed A row g = mt*16 + q*4 + r; image = (4*mt+q)/9 (compile-time
    // split; 36 = 4*9 so boundaries fall on q-quads), region = g - 36*image.
    // B col: tile-aligned -- sentence = c0 + (nt>>1), word jj = (nt&1)*16+l15.
    int il[4];
    #pragma unroll
    for (int bb = 0; bb < 4; ++bb) il[bb] = im_len[b0 + bb] - 1;   // in [9, 36]

    float sc[4][2] = {{0.f,0.f},{0.f,0.f},{0.f,0.f},{0.f,0.f}};
    #pragma unroll
    for (int t = 0; t < 4; ++t) {
        const int nt = wave * 4 + t;
        const int c  = c0 + (nt >> 1);
        const int sl = s_len[c] - 3;                 // valid words, in [5, 30]
        const int jj = (nt & 1) * 16 + l15;          // word index within sentence
        const bool jv = (jj < sl);

        float m[4] = {-3.4e38f, -3.4e38f, -3.4e38f, -3.4e38f};
        #pragma unroll
        for (int mt = 0; mt < 9; ++mt) {
            const int im_lo = (4 * mt) / 9;          // compile-time
            const int im_hi = (4 * mt + 3) / 9;      // compile-time
            const int thr   = 9 * im_hi - 4 * mt;    // q >= thr -> im_hi
            #pragma unroll
            for (int r = 0; r < 4; ++r) {
                const float v = acc[mt][t][r];
                const int base = mt * 16 + q * 4 + r;
                if (im_lo == im_hi) {
                    const int i = base - 36 * im_lo;
                    if (i < il[im_lo]) m[im_lo] = fmaxf(m[im_lo], v);
                } else {
                    const bool hi = (q >= thr);
                    if (!hi) {
                        const int i = base - 36 * im_lo;
                        if (i < il[im_lo]) m[im_lo] = fmaxf(m[im_lo], v);
                    } else {
                        const int i = base - 36 * im_hi;
                        if (i < il[im_hi]) m[im_hi] = fmaxf(m[im_hi], v);
                    }
                }
            }
        }
        #pragma unroll
        for (int bb = 0; bb < 4; ++bb) {
            float mm = m[bb];
            // combine the 4 row-quads -> full max over image bb's regions
            mm = fmaxf(mm, __shfl_xor(mm, 16, 64));
            mm = fmaxf(mm, __shfl_xor(mm, 32, 64));
            // masked (zeroed) entries participate in the max only when il < 36
            if (il[bb] < LI) mm = fmaxf(mm, 0.f);
            float v = (q == 0 && jv) ? mm : 0.f;     // count each column once
            #pragma unroll
            for (int off = 32; off >= 1; off >>= 1) v += __shfl_xor(v, off, 64);
            sc[bb][t >> 1] += v;
        }
    }
    if (lane == 0) {
        #pragma unroll
        for (int bb = 0; bb < 4; ++bb)
            #pragma unroll
            for (int h = 0; h < 2; ++h)
                scores[(b0 + bb) * NB + c0 + wave * 2 + h] = sc[bb][h];
    }
}

// Fused contrastive loss: 64 blocks x 4 waves; wave handles row/col t of the
// score matrix; block-level sum -> one atomicAdd into out[0].
__global__ __launch_bounds__(256) void loss_fused(
    const float* __restrict__ sc, float* __restrict__ out)
{
    const int wave = threadIdx.x >> 6, lane = threadIdx.x & 63;
    const int t = blockIdx.x * 4 + wave;
    const float dt = sc[t * (NB + 1)];
    float rowmax = 0.f, colmax = 0.f;
    #pragma unroll
    for (int p = 0; p < 4; ++p) {
        const int k = lane + 64 * p;
        const float r = sc[t * NB + k];
        const float c = sc[k * NB + t];
        if (k != t) {
            rowmax = fmaxf(rowmax, 0.2f + r - dt);
            colmax = fmaxf(colmax, 0.2f + c - dt);
        }
    }
    #pragma unroll
    for (int o = 32; o >= 1; o >>= 1) {
        rowmax = fmaxf(rowmax, __shfl_xor(rowmax, o, 64));
        colmax = fmaxf(colmax, __shfl_xor(colmax, o, 64));
    }
    __shared__ float red[4];
    if (lane == 0) red[wave] = fmaxf(rowmax, 0.f) + fmaxf(colmax, 0.f);
    __syncthreads();
    if (threadIdx.x == 0)
        atomicAdd(out, red[0] + red[1] + red[2] + red[3]);
}

extern "C" void kernel_launch(void* const* d_in, const int* in_sizes, int n_in,
                              void* d_out, int out_size, void* d_ws, size_t ws_size,
                              hipStream_t stream) {
    const float* im_set = (const float*)d_in[0];
    const float* s_seq  = (const float*)d_in[1];
    const int*   im_len = (const int*)d_in[2];
    const int*   s_len  = (const int*)d_in[3];
    float* out = (float*)d_out;

    char* ws = (char*)d_ws;
    const size_t imp_bytes = (size_t)NB * LIP * DIM * 2;   // 18.9 MB (dense)
    const size_t sp_bytes  = (size_t)NB * LSP * DIM * 2;   // 16.8 MB (padded)
    short* imp    = (short*)ws;
    short* sp     = (short*)(ws + imp_bytes);
    float* scores = (float*)(ws + imp_bytes + sp_bytes);   // 256 KB

    // 17408 rows, two per wave -> 8704 waves -> 2176 blocks
    normalize_pack<<<2176, 256, 0, stream>>>(im_set, s_seq, imp, sp);

    dim3 grid(NB / 4, NB / 8);
    gemm_scores<<<grid, 256, 0, stream>>>(imp, sp, im_len, s_len, scores);

    loss_fused<<<64, 256, 0, stream>>>(scores, out);
}